// Round 4
// baseline (2008.774 us; speedup 1.0000x reference)
//
#include <hip/hip_runtime.h>

typedef unsigned short ushort;
typedef unsigned int uint;
typedef __bf16 bf16_t;
typedef bf16_t bf16x8 __attribute__((ext_vector_type(8)));
typedef float f32x4 __attribute__((ext_vector_type(4)));

#define B_ 2048
#define T_ 512
#define D_ 5
#define H_ 128
#define C_ 10
#define BT 16      // batch tile per workgroup
#define BLK 256    // 4 waves -> 1 wave/SIMD -> full 512-reg unified budget
#define H0STR 168  // h0s row stride in ushorts (160 used + 8 pad)
#define H1STR 136  // h1s row stride (128 used + 8 pad)

static __device__ __forceinline__ float b2f(ushort u) {
    return __builtin_bit_cast(float, ((uint)u) << 16);
}
static __device__ __forceinline__ ushort f2b(float f) {
    uint u = __builtin_bit_cast(uint, f);
    u += 0x7FFFu + ((u >> 16) & 1u);   // RNE
    return (ushort)(u >> 16);
}
// inf-safe: exp->inf => rcp->0 => sigmoid->0/1, tanh->+-1
static __device__ __forceinline__ float sigf(float x) {
    return __builtin_amdgcn_rcpf(1.0f + __expf(-x));
}
static __device__ __forceinline__ float tanhf_(float x) {
    return 1.0f - 2.0f * __builtin_amdgcn_rcpf(1.0f + __expf(2.0f * x));
}
// dual-dtype scalar load: m32 ? float32 : bf16
static __device__ __forceinline__ float ldf(const void* p, long i, bool m32) {
    return m32 ? ((const float*)p)[i] : b2f(((const ushort*)p)[i]);
}
static __device__ __forceinline__ bf16x8 ld16(const ushort* p) {
    return __builtin_bit_cast(bf16x8, *(const uint4*)p);
}
// dual-dtype 8-element fragment load (init-time only)
static __device__ __forceinline__ bf16x8 ldfrag(const void* p, long idx, bool m32) {
    if (!m32) return ld16((const ushort*)p + idx);
    const float* f = (const float*)p + idx;
    union { ushort u[8]; bf16x8 v; } r;
#pragma unroll
    for (int j = 0; j < 8; ++j) r.u[j] = f2b(f[j]);
    return r.v;
}
static __device__ __forceinline__ f32x4 splat4(float v) {
    f32x4 r = {v, v, v, v};
    return r;
}

// ---- dtype detector (unchanged; picked f32, passed R2/R3)
__global__ void detect_dtype(const ushort* __restrict__ w, int* __restrict__ flag) {
    __shared__ int cnt;
    if (threadIdx.x == 0) cnt = 0;
    __syncthreads();
    int local = 0;
    for (int i = threadIdx.x; i < 16384; i += 256)
        if ((uint)(w[i] & 0x7F80u) >= 0x4180u) ++local;   // |v| >= 16
    atomicAdd(&cnt, local);
    __syncthreads();
    if (threadIdx.x == 0) *flag = (cnt > 512) ? 1 : 0;
}

__global__ __launch_bounds__(BLK, 1) void lstm2_fused(
    const void* __restrict__ x,
    const void* __restrict__ wih0, const void* __restrict__ whh0,
    const void* __restrict__ bih0, const void* __restrict__ bhh0,
    const void* __restrict__ wih1, const void* __restrict__ whh1,
    const void* __restrict__ bih1, const void* __restrict__ bhh1,
    const void* __restrict__ cw1, const void* __restrict__ cb1,
    const void* __restrict__ cw2, const void* __restrict__ cb2,
    const int* __restrict__ flag, void* __restrict__ out)
{
    __shared__ __align__(16) ushort h0s[2][BT * H0STR]; // [.][row][0..127]=h0, [128..132]=x_t, rest 0
    __shared__ __align__(16) ushort h1s[2][BT * H1STR];
    __shared__ float rs[BT * 64];                       // classifier hidden
    __shared__ uint4 xstash[8 * 4 * 64];                // x-tile B-frags: [(g*2+s)*4+w][lane], 32 KB

    const bool m32 = (*flag) != 0;   // uniform
    const int tid  = threadIdx.x;
    const int w    = tid >> 6;       // wave 0..3
    const int lane = tid & 63;
    const int quad = lane >> 4;
    const int l16  = lane & 15;
    const int bt0  = blockIdx.x * BT;

    // ---- stage x(0) into buf0 cols 128..159; zeros into buf1 (bias col is gone:
    // bias now rides in the accumulator init)
    for (int i = tid; i < BT * 32; i += BLK) {
        int row = i >> 5, cc = i & 31;
        ushort v0 = (cc < 5) ? f2b(ldf(x, ((long)(bt0 + row) * T_) * D_ + cc, m32)) : (ushort)0;
        h0s[0][row * H0STR + 128 + cc] = v0;
        h0s[1][row * H0STR + 128 + cc] = 0;
    }
    // zero h1s[1] (h1(-1) = 0, read at iter 0)
    for (int i = tid; i < BT * H_; i += BLK) {
        int row = i >> 7, cc = i & 127;
        h1s[1][row * H1STR + cc] = 0;
    }

    // ---- register-resident weight fragments. Each wave: 4 gates x 2 n-subtiles.
    // B-frag (16x16x32): lane holds W[n][k = kt*32 + quad*8 + j], j=0..7
    bf16x8 wh0c[4][2][4]; // layer0 recurrent (w_hh0)
    bf16x8 wi1f[4][2][4]; // layer1, h0 part
    bf16x8 wh1f[4][2][4]; // layer1, h1 part
    float  b0v[4][2], b1v[4][2];
#pragma unroll
    for (int g = 0; g < 4; ++g) {
#pragma unroll
        for (int s = 0; s < 2; ++s) {
            const int n = g * 128 + w * 32 + s * 16 + l16; // row in 4H=512 gate dim
#pragma unroll
            for (int kt = 0; kt < 4; ++kt) {
                wh0c[g][s][kt] = ldfrag(whh0, (long)n * 128 + kt * 32 + quad * 8, m32);
                wi1f[g][s][kt] = ldfrag(wih1, (long)n * 128 + kt * 32 + quad * 8, m32);
                wh1f[g][s][kt] = ldfrag(whh1, (long)n * 128 + kt * 32 + quad * 8, m32);
            }
            // x-tile frag (w_ih0, K slots 0..4 live on quad==0) -> LDS stash
            union { ushort u[8]; uint4 q; } xt;
            xt.q = make_uint4(0, 0, 0, 0);
            if (quad == 0) {
#pragma unroll
                for (int j = 0; j < 5; ++j) xt.u[j] = f2b(ldf(wih0, (long)n * D_ + j, m32));
            }
            xstash[((g * 2 + s) * 4 + w) * 64 + lane] = xt.q;
            b0v[g][s] = ldf(bih0, n, m32) + ldf(bhh0, n, m32);
            b1v[g][s] = ldf(bih1, n, m32) + ldf(bhh1, n, m32);
        }
    }

    __syncthreads();

    // ---- recurrent state
    bf16x8 h0f[4];
    {
        uint4 z = make_uint4(0, 0, 0, 0);
        h0f[0] = h0f[1] = h0f[2] = h0f[3] = __builtin_bit_cast(bf16x8, z); // h0(-1)=0
    }
    f32x4 c0[2] = {splat4(0.f), splat4(0.f)};
    f32x4 c1[2] = {splat4(0.f), splat4(0.f)};
    const int xr = tid / 5, xc = tid - (tid / 5) * 5; // x stagers (tid < 80)

#pragma unroll 1
    for (int t = 0; t < T_; ++t) {
        const int wb = (t + 1) & 1; // buffer produced this iter
        const int rb = t & 1;       // buffer produced last iter (holds h0(t-1), x(t))
        // prefetch x(t+1): global latency hides under layer-0 compute
        float xv = 0.f;
        const bool stage = (tid < 80) && (t < T_ - 1);
        if (stage) xv = ldf(x, ((long)(bt0 + xr) * T_ + (t + 1)) * D_ + xc, m32);

        // ---- layer 0: gates = h0(t-1) @ w_hh0^T + x(t) @ w_ih0^T + b0
        f32x4 a[4][2];
#pragma unroll
        for (int g = 0; g < 4; ++g)
#pragma unroll
            for (int s = 0; s < 2; ++s) a[g][s] = splat4(b0v[g][s]);
#pragma unroll
        for (int kt = 0; kt < 4; ++kt)
#pragma unroll
            for (int g = 0; g < 4; ++g)
#pragma unroll
                for (int s = 0; s < 2; ++s)
                    a[g][s] = __builtin_amdgcn_mfma_f32_16x16x32_bf16(
                        h0f[kt], wh0c[g][s][kt], a[g][s], 0, 0, 0);
        {
            // kt=4: x part. A-frag JIT from LDS, B-frags JIT from stash.
            bf16x8 ha4 = ld16(&h0s[rb][l16 * H0STR + 128 + quad * 8]);
#pragma unroll
            for (int g = 0; g < 4; ++g)
#pragma unroll
                for (int s = 0; s < 2; ++s) {
                    bf16x8 xb = __builtin_bit_cast(bf16x8,
                        xstash[((g * 2 + s) * 4 + w) * 64 + lane]);
                    a[g][s] = __builtin_amdgcn_mfma_f32_16x16x32_bf16(
                        ha4, xb, a[g][s], 0, 0, 0);
                }
        }
        ushort h0w[2][4];
#pragma unroll
        for (int s = 0; s < 2; ++s)
#pragma unroll
            for (int r = 0; r < 4; ++r) {
                float iv = sigf(a[0][s][r]), fv = sigf(a[1][s][r]);
                float gv = tanhf_(a[2][s][r]), ov = sigf(a[3][s][r]);
                float cv = fv * c0[s][r] + iv * gv;
                c0[s][r] = cv;
                h0w[s][r] = f2b(ov * tanhf_(cv));
            }

        // write h0(t) + x(t+1) into buffer wb
#pragma unroll
        for (int s = 0; s < 2; ++s)
#pragma unroll
            for (int r = 0; r < 4; ++r)
                h0s[wb][(quad * 4 + r) * H0STR + w * 32 + s * 16 + l16] = h0w[s][r];
        if (stage) h0s[wb][xr * H0STR + 128 + xc] = f2b(xv);

        __syncthreads(); // single barrier per step

        // reload persistent h0 frags (serve layer-1 now AND layer-0 of step t+1)
#pragma unroll
        for (int kt = 0; kt < 4; ++kt)
            h0f[kt] = ld16(&h0s[wb][l16 * H0STR + kt * 32 + quad * 8]);

        // ---- layer 1: gates = h0(t) @ w_ih1^T + h1(t-1) @ w_hh1^T + b1
#pragma unroll
        for (int g = 0; g < 4; ++g)
#pragma unroll
            for (int s = 0; s < 2; ++s) a[g][s] = splat4(b1v[g][s]);
#pragma unroll
        for (int kt = 0; kt < 4; ++kt)
#pragma unroll
            for (int g = 0; g < 4; ++g)
#pragma unroll
                for (int s = 0; s < 2; ++s)
                    a[g][s] = __builtin_amdgcn_mfma_f32_16x16x32_bf16(
                        h0f[kt], wi1f[g][s][kt], a[g][s], 0, 0, 0);
#pragma unroll
        for (int kt = 0; kt < 4; ++kt) {
            bf16x8 hb = ld16(&h1s[wb][l16 * H1STR + kt * 32 + quad * 8]); // JIT
#pragma unroll
            for (int g = 0; g < 4; ++g)
#pragma unroll
                for (int s = 0; s < 2; ++s)
                    a[g][s] = __builtin_amdgcn_mfma_f32_16x16x32_bf16(
                        hb, wh1f[g][s][kt], a[g][s], 0, 0, 0);
        }
#pragma unroll
        for (int s = 0; s < 2; ++s)
#pragma unroll
            for (int r = 0; r < 4; ++r) {
                float iv = sigf(a[0][s][r]), fv = sigf(a[1][s][r]);
                float gv = tanhf_(a[2][s][r]), ov = sigf(a[3][s][r]);
                float cv = fv * c1[s][r] + iv * gv;
                c1[s][r] = cv;
                // h1(t) -> buffer read at iter t+1; WAR-safe across barrier(t)
                h1s[wb ^ 1][(quad * 4 + r) * H1STR + w * 32 + s * 16 + l16]
                    = f2b(ov * tanhf_(cv));
            }
    }

    __syncthreads(); // final h1 writes (h1s[1]) visible to all threads

    // ---- classifier: r = relu(h1 @ cw1^T + cb1); out = r @ cw2^T + cb2
    // h1(T-1) lives in h1s[1] (T even: last write went to buffer (T-1)&1 = 1)
    {
        int m = tid >> 4, j0 = (tid & 15) * 4; // 16 rows x 16 threads, 4 outs each
        float s0 = ldf(cb1, j0, m32), s1 = ldf(cb1, j0 + 1, m32);
        float s2 = ldf(cb1, j0 + 2, m32), s3 = ldf(cb1, j0 + 3, m32);
        const ushort* hr = &h1s[1][m * H1STR];
#pragma unroll 4
        for (int k = 0; k < 128; ++k) {
            float hv = b2f(hr[k]);
            s0 += hv * ldf(cw1, (long)j0 * 128 + k, m32);
            s1 += hv * ldf(cw1, (long)(j0 + 1) * 128 + k, m32);
            s2 += hv * ldf(cw1, (long)(j0 + 2) * 128 + k, m32);
            s3 += hv * ldf(cw1, (long)(j0 + 3) * 128 + k, m32);
        }
        rs[m * 64 + j0]     = fmaxf(s0, 0.f);
        rs[m * 64 + j0 + 1] = fmaxf(s1, 0.f);
        rs[m * 64 + j0 + 2] = fmaxf(s2, 0.f);
        rs[m * 64 + j0 + 3] = fmaxf(s3, 0.f);
    }
    __syncthreads();
    if (tid < 160) {
        int m = tid / 10, cc = tid - m * 10;
        float s = ldf(cb2, cc, m32);
#pragma unroll
        for (int j = 0; j < 64; ++j) s += rs[m * 64 + j] * ldf(cw2, (long)cc * 64 + j, m32);
        long oi = (long)(bt0 + m) * C_ + cc;
        if (m32) ((float*)out)[oi] = s; else ((ushort*)out)[oi] = f2b(s);
    }
    // last_hidden output (from h1s[1], bf16-rounded recurrent state)
    for (int idx = tid; idx < BT * H_; idx += BLK) {
        int m = idx >> 7, k = idx & 127;
        float v = b2f(h1s[1][m * H1STR + k]);
        long oi = (long)B_ * C_ + (long)(bt0 + m) * H_ + k;
        if (m32) ((float*)out)[oi] = v; else ((ushort*)out)[oi] = f2b(v);
    }
}

extern "C" void kernel_launch(void* const* d_in, const int* in_sizes, int n_in,
                              void* d_out, int out_size, void* d_ws, size_t ws_size,
                              hipStream_t stream) {
    (void)in_sizes; (void)n_in; (void)out_size; (void)ws_size;
    int* flag = (int*)d_ws;
    hipLaunchKernelGGL(detect_dtype, dim3(1), dim3(256), 0, stream,
                       (const ushort*)d_in[2], flag);
    hipLaunchKernelGGL(lstm2_fused, dim3(B_ / BT), dim3(BLK), 0, stream,
                       d_in[0], d_in[1], d_in[2], d_in[3], d_in[4],
                       d_in[5], d_in[6], d_in[7], d_in[8],
                       d_in[9], d_in[10], d_in[11], d_in[12],
                       (const int*)flag, d_out);
}

// Round 5
// 1720.667 us; speedup vs baseline: 1.1674x; 1.1674x over previous
//
#include <hip/hip_runtime.h>

typedef unsigned short ushort;
typedef unsigned int uint;
typedef __bf16 bf16_t;
typedef bf16_t bf16x8 __attribute__((ext_vector_type(8)));
typedef float f32x4 __attribute__((ext_vector_type(4)));

#define B_ 2048
#define T_ 512
#define D_ 5
#define H_ 128
#define C_ 10
#define BT 16      // batch tile per workgroup
#define BLK 512    // 8 waves -> 2 waves/SIMD: 256-reg budget, 2-way latency hiding
#define H0STR 168  // h0s row stride in ushorts (160 used + 8 pad)
#define H1STR 136  // h1s row stride (128 used + 8 pad)

static __device__ __forceinline__ float b2f(ushort u) {
    return __builtin_bit_cast(float, ((uint)u) << 16);
}
static __device__ __forceinline__ ushort f2b(float f) {
    uint u = __builtin_bit_cast(uint, f);
    u += 0x7FFFu + ((u >> 16) & 1u);   // RNE
    return (ushort)(u >> 16);
}
// inf-safe: exp->inf => rcp->0 => sigmoid->0/1, tanh->+-1
static __device__ __forceinline__ float sigf(float x) {
    return __builtin_amdgcn_rcpf(1.0f + __expf(-x));
}
static __device__ __forceinline__ float tanhf_(float x) {
    return 1.0f - 2.0f * __builtin_amdgcn_rcpf(1.0f + __expf(2.0f * x));
}
// dual-dtype scalar load: m32 ? float32 : bf16
static __device__ __forceinline__ float ldf(const void* p, long i, bool m32) {
    return m32 ? ((const float*)p)[i] : b2f(((const ushort*)p)[i]);
}
static __device__ __forceinline__ bf16x8 ld16(const ushort* p) {
    return __builtin_bit_cast(bf16x8, *(const uint4*)p);
}
// dual-dtype 8-element fragment load (init-time only)
static __device__ __forceinline__ bf16x8 ldfrag(const void* p, long idx, bool m32) {
    if (!m32) return ld16((const ushort*)p + idx);
    const float* f = (const float*)p + idx;
    union { ushort u[8]; bf16x8 v; } r;
#pragma unroll
    for (int j = 0; j < 8; ++j) r.u[j] = f2b(f[j]);
    return r.v;
}
static __device__ __forceinline__ f32x4 splat4(float v) {
    f32x4 r = {v, v, v, v};
    return r;
}

// ---- dtype detector (unchanged; picked f32, passed R2-R4)
__global__ void detect_dtype(const ushort* __restrict__ w, int* __restrict__ flag) {
    __shared__ int cnt;
    if (threadIdx.x == 0) cnt = 0;
    __syncthreads();
    int local = 0;
    for (int i = threadIdx.x; i < 16384; i += 256)
        if ((uint)(w[i] & 0x7F80u) >= 0x4180u) ++local;   // |v| >= 16
    atomicAdd(&cnt, local);
    __syncthreads();
    if (threadIdx.x == 0) *flag = (cnt > 512) ? 1 : 0;
}

__global__ __launch_bounds__(BLK, 2) void lstm2_fused(
    const void* __restrict__ x,
    const void* __restrict__ wih0, const void* __restrict__ whh0,
    const void* __restrict__ bih0, const void* __restrict__ bhh0,
    const void* __restrict__ wih1, const void* __restrict__ whh1,
    const void* __restrict__ bih1, const void* __restrict__ bhh1,
    const void* __restrict__ cw1, const void* __restrict__ cb1,
    const void* __restrict__ cw2, const void* __restrict__ cb2,
    const int* __restrict__ flag, void* __restrict__ out)
{
    __shared__ __align__(16) ushort h0s[2][BT * H0STR]; // [.][row][0..127]=h0, [128..132]=x_t, rest 0
    __shared__ __align__(16) ushort h1s[2][BT * H1STR];
    __shared__ float rs[BT * 64];                       // classifier hidden
    __shared__ uint4 xstash[4 * 8 * 64];                // x-tile B-frags: [(g*8+w)][lane], 32 KB

    const bool m32 = (*flag) != 0;   // uniform
    const int tid  = threadIdx.x;
    const int w    = tid >> 6;       // wave 0..7 -> owns n-subtile cols [w*16, w*16+16)
    const int lane = tid & 63;
    const int quad = lane >> 4;
    const int l16  = lane & 15;
    const int bt0  = blockIdx.x * BT;

    // ---- stage x(0) into buf0 cols 128..159; zeros into buf1
    for (int i = tid; i < BT * 32; i += BLK) {
        int row = i >> 5, cc = i & 31;
        ushort v0 = (cc < 5) ? f2b(ldf(x, ((long)(bt0 + row) * T_) * D_ + cc, m32)) : (ushort)0;
        h0s[0][row * H0STR + 128 + cc] = v0;
        h0s[1][row * H0STR + 128 + cc] = 0;
    }
    // zero h1s[1] (h1(-1) = 0, read at iter 0)
    for (int i = tid; i < BT * H_; i += BLK) {
        int row = i >> 7, cc = i & 127;
        h1s[1][row * H1STR + cc] = 0;
    }

    // ---- register-resident weight fragments. Each wave: 4 gates x 1 subtile.
    // B-frag (16x16x32): lane holds W[n][k = kt*32 + quad*8 + j], j=0..7
    bf16x8 wh0c[4][4]; // layer0 recurrent (w_hh0)    [g][kt]
    bf16x8 wi1f[4][4]; // layer1, h0 part (w_ih1)
    bf16x8 wh1f[4][4]; // layer1, h1 part (w_hh1)
    float  b0v[4], b1v[4];
#pragma unroll
    for (int g = 0; g < 4; ++g) {
        const int n = g * 128 + w * 16 + l16; // row in 4H=512 gate dim
#pragma unroll
        for (int kt = 0; kt < 4; ++kt) {
            wh0c[g][kt] = ldfrag(whh0, (long)n * 128 + kt * 32 + quad * 8, m32);
            wi1f[g][kt] = ldfrag(wih1, (long)n * 128 + kt * 32 + quad * 8, m32);
            wh1f[g][kt] = ldfrag(whh1, (long)n * 128 + kt * 32 + quad * 8, m32);
        }
        // x-tile frag (w_ih0, K slots 0..4 live on quad==0) -> LDS stash
        union { ushort u[8]; uint4 q; } xt;
        xt.q = make_uint4(0, 0, 0, 0);
        if (quad == 0) {
#pragma unroll
            for (int j = 0; j < 5; ++j) xt.u[j] = f2b(ldf(wih0, (long)n * D_ + j, m32));
        }
        xstash[(g * 8 + w) * 64 + lane] = xt.q;
        b0v[g] = ldf(bih0, n, m32) + ldf(bhh0, n, m32);
        b1v[g] = ldf(bih1, n, m32) + ldf(bhh1, n, m32);
    }

    __syncthreads();

    // ---- recurrent state
    bf16x8 h0f[4];
    {
        uint4 z = make_uint4(0, 0, 0, 0);
        h0f[0] = h0f[1] = h0f[2] = h0f[3] = __builtin_bit_cast(bf16x8, z); // h0(-1)=0
    }
    f32x4 c0 = splat4(0.f), c1 = splat4(0.f);
    const int xr = tid / 5, xc = tid - (tid / 5) * 5; // x stagers (tid < 80)

#pragma unroll 1
    for (int t = 0; t < T_; ++t) {
        const int wb = (t + 1) & 1; // buffer produced this iter
        const int rb = t & 1;       // buffer produced last iter (holds h0(t-1), x(t))
        // prefetch x(t+1): global latency hides under layer-0 compute
        float xv = 0.f;
        const bool stage = (tid < 80) && (t < T_ - 1);
        if (stage) xv = ldf(x, ((long)(bt0 + xr) * T_ + (t + 1)) * D_ + xc, m32);

        // ---- layer 0: gates = h0(t-1) @ w_hh0^T + x(t) @ w_ih0^T + b0
        f32x4 a[4];
#pragma unroll
        for (int g = 0; g < 4; ++g) a[g] = splat4(b0v[g]);
#pragma unroll
        for (int kt = 0; kt < 4; ++kt)
#pragma unroll
            for (int g = 0; g < 4; ++g)
                a[g] = __builtin_amdgcn_mfma_f32_16x16x32_bf16(
                    h0f[kt], wh0c[g][kt], a[g], 0, 0, 0);
        {
            // kt=4: x part. A-frag JIT from LDS, B-frags JIT from stash.
            bf16x8 ha4 = ld16(&h0s[rb][l16 * H0STR + 128 + quad * 8]);
#pragma unroll
            for (int g = 0; g < 4; ++g) {
                bf16x8 xb = __builtin_bit_cast(bf16x8, xstash[(g * 8 + w) * 64 + lane]);
                a[g] = __builtin_amdgcn_mfma_f32_16x16x32_bf16(ha4, xb, a[g], 0, 0, 0);
            }
        }
        ushort h0w[4];
#pragma unroll
        for (int r = 0; r < 4; ++r) {
            float iv = sigf(a[0][r]), fv = sigf(a[1][r]);
            float gv = tanhf_(a[2][r]), ov = sigf(a[3][r]);
            float cv = fv * c0[r] + iv * gv;
            c0[r] = cv;
            h0w[r] = f2b(ov * tanhf_(cv));
        }

        // write h0(t) + x(t+1) into buffer wb
#pragma unroll
        for (int r = 0; r < 4; ++r)
            h0s[wb][(quad * 4 + r) * H0STR + w * 16 + l16] = h0w[r];
        if (stage) h0s[wb][xr * H0STR + 128 + xc] = f2b(xv);

        __syncthreads(); // single barrier per step

        // reload persistent h0 frags (serve layer-1 now AND layer-0 of step t+1)
#pragma unroll
        for (int kt = 0; kt < 4; ++kt)
            h0f[kt] = ld16(&h0s[wb][l16 * H0STR + kt * 32 + quad * 8]);

        // ---- layer 1: gates = h0(t) @ w_ih1^T + h1(t-1) @ w_hh1^T + b1
#pragma unroll
        for (int g = 0; g < 4; ++g) a[g] = splat4(b1v[g]);
#pragma unroll
        for (int kt = 0; kt < 4; ++kt)
#pragma unroll
            for (int g = 0; g < 4; ++g)
                a[g] = __builtin_amdgcn_mfma_f32_16x16x32_bf16(
                    h0f[kt], wi1f[g][kt], a[g], 0, 0, 0);
#pragma unroll
        for (int kt = 0; kt < 4; ++kt) {
            bf16x8 hb = ld16(&h1s[wb][l16 * H1STR + kt * 32 + quad * 8]); // JIT
#pragma unroll
            for (int g = 0; g < 4; ++g)
                a[g] = __builtin_amdgcn_mfma_f32_16x16x32_bf16(
                    hb, wh1f[g][kt], a[g], 0, 0, 0);
        }
#pragma unroll
        for (int r = 0; r < 4; ++r) {
            float iv = sigf(a[0][r]), fv = sigf(a[1][r]);
            float gv = tanhf_(a[2][r]), ov = sigf(a[3][r]);
            float cv = fv * c1[r] + iv * gv;
            c1[r] = cv;
            // h1(t) -> buffer read at iter t+1; WAR-safe across barrier(t)
            h1s[wb ^ 1][(quad * 4 + r) * H1STR + w * 16 + l16] = f2b(ov * tanhf_(cv));
        }
    }

    __syncthreads(); // final h1 writes (h1s[1]) visible to all threads

    // ---- classifier: r = relu(h1 @ cw1^T + cb1); out = r @ cw2^T + cb2
    // h1(T-1) lives in h1s[1] (T even: last write went to buffer (T-1)&1 = 1)
    if (tid < 256) {
        int m = tid >> 4, j0 = (tid & 15) * 4; // 16 rows x 16 threads, 4 outs each
        float s0 = ldf(cb1, j0, m32), s1 = ldf(cb1, j0 + 1, m32);
        float s2 = ldf(cb1, j0 + 2, m32), s3 = ldf(cb1, j0 + 3, m32);
        const ushort* hr = &h1s[1][m * H1STR];
#pragma unroll 4
        for (int k = 0; k < 128; ++k) {
            float hv = b2f(hr[k]);
            s0 += hv * ldf(cw1, (long)j0 * 128 + k, m32);
            s1 += hv * ldf(cw1, (long)(j0 + 1) * 128 + k, m32);
            s2 += hv * ldf(cw1, (long)(j0 + 2) * 128 + k, m32);
            s3 += hv * ldf(cw1, (long)(j0 + 3) * 128 + k, m32);
        }
        rs[m * 64 + j0]     = fmaxf(s0, 0.f);
        rs[m * 64 + j0 + 1] = fmaxf(s1, 0.f);
        rs[m * 64 + j0 + 2] = fmaxf(s2, 0.f);
        rs[m * 64 + j0 + 3] = fmaxf(s3, 0.f);
    }
    __syncthreads();
    if (tid < 160) {
        int m = tid / 10, cc = tid - m * 10;
        float s = ldf(cb2, cc, m32);
#pragma unroll
        for (int j = 0; j < 64; ++j) s += rs[m * 64 + j] * ldf(cw2, (long)cc * 64 + j, m32);
        long oi = (long)(bt0 + m) * C_ + cc;
        if (m32) ((float*)out)[oi] = s; else ((ushort*)out)[oi] = f2b(s);
    }
    // last_hidden output (from h1s[1], bf16-rounded recurrent state)
    for (int idx = tid; idx < BT * H_; idx += BLK) {
        int m = idx >> 7, k = idx & 127;
        float v = b2f(h1s[1][m * H1STR + k]);
        long oi = (long)B_ * C_ + (long)(bt0 + m) * H_ + k;
        if (m32) ((float*)out)[oi] = v; else ((ushort*)out)[oi] = f2b(v);
    }
}

extern "C" void kernel_launch(void* const* d_in, const int* in_sizes, int n_in,
                              void* d_out, int out_size, void* d_ws, size_t ws_size,
                              hipStream_t stream) {
    (void)in_sizes; (void)n_in; (void)out_size; (void)ws_size;
    int* flag = (int*)d_ws;
    hipLaunchKernelGGL(detect_dtype, dim3(1), dim3(256), 0, stream,
                       (const ushort*)d_in[2], flag);
    hipLaunchKernelGGL(lstm2_fused, dim3(B_ / BT), dim3(BLK), 0, stream,
                       d_in[0], d_in[1], d_in[2], d_in[3], d_in[4],
                       d_in[5], d_in[6], d_in[7], d_in[8],
                       d_in[9], d_in[10], d_in[11], d_in[12],
                       (const int*)flag, d_out);
}

// Round 6
// 980.789 us; speedup vs baseline: 2.0481x; 1.7544x over previous
//
#include <hip/hip_runtime.h>

typedef unsigned short ushort;
typedef unsigned int uint;
typedef __bf16 bf16_t;
typedef bf16_t bf16x8 __attribute__((ext_vector_type(8)));
typedef float f32x4 __attribute__((ext_vector_type(4)));

#define B_ 2048
#define T_ 512
#define D_ 5
#define H_ 128
#define C_ 10
#define BT 16      // batch tile per workgroup
#define BLK 512    // 8 waves, 2 waves/SIMD
#define NP 128     // producer/consumer pair count
#define CH 8       // pipeline chunk (steps per sync)
#define H0STR 168  // LDS row stride in ushorts (h0 row 128 + x cols + pad)
#define H1STR 136  // h1 row stride (128 + 8 pad)

static __device__ __forceinline__ float b2f(ushort u) {
    return __builtin_bit_cast(float, ((uint)u) << 16);
}
static __device__ __forceinline__ ushort f2b(float f) {
    uint u = __builtin_bit_cast(uint, f);
    u += 0x7FFFu + ((u >> 16) & 1u);   // RNE
    return (ushort)(u >> 16);
}
// inf-safe: exp->inf => rcp->0 => sigmoid->0/1, tanh->+-1
static __device__ __forceinline__ float sigf(float x) {
    return __builtin_amdgcn_rcpf(1.0f + __expf(-x));
}
static __device__ __forceinline__ float tanhf_(float x) {
    return 1.0f - 2.0f * __builtin_amdgcn_rcpf(1.0f + __expf(2.0f * x));
}
static __device__ __forceinline__ float ldf(const void* p, long i, bool m32) {
    return m32 ? ((const float*)p)[i] : b2f(((const ushort*)p)[i]);
}
static __device__ __forceinline__ bf16x8 ld16(const ushort* p) {
    return __builtin_bit_cast(bf16x8, *(const uint4*)p);
}
static __device__ __forceinline__ bf16x8 ldfrag(const void* p, long idx, bool m32) {
    if (!m32) return ld16((const ushort*)p + idx);
    const float* f = (const float*)p + idx;
    union { ushort u[8]; bf16x8 v; } r;
#pragma unroll
    for (int j = 0; j < 8; ++j) r.u[j] = f2b(f[j]);
    return r.v;
}
static __device__ __forceinline__ f32x4 splat4(float v) {
    f32x4 r = {v, v, v, v};
    return r;
}

// ---- dtype detector (proven R2-R5; picks f32)
__global__ void detect_dtype(const ushort* __restrict__ w, int* __restrict__ flag) {
    __shared__ int cnt;
    if (threadIdx.x == 0) cnt = 0;
    __syncthreads();
    int local = 0;
    for (int i = threadIdx.x; i < 16384; i += 256)
        if ((uint)(w[i] & 0x7F80u) >= 0x4180u) ++local;   // |v| >= 16
    atomicAdd(&cnt, local);
    __syncthreads();
    if (threadIdx.x == 0) *flag = (cnt > 512) ? 1 : 0;
}

// ---- zero the pipeline progress flags (d_ws is poisoned before each launch)
__global__ void init_flags(int* __restrict__ prog) {
    prog[threadIdx.x] = 0;   // 256 ints: prog_p[128], prog_c[128]
}

// =====================================================================
// Pipelined kernel: block p<NP = layer-0 producer; block NP+p = layer-1
// consumer + classifier. h0 streamed via ring FIFO (F slots) in d_ws.
// =====================================================================
__global__ __launch_bounds__(BLK, 2) void lstm2_pipe(
    const void* __restrict__ x,
    const void* __restrict__ wih0, const void* __restrict__ whh0,
    const void* __restrict__ bih0, const void* __restrict__ bhh0,
    const void* __restrict__ wih1, const void* __restrict__ whh1,
    const void* __restrict__ bih1, const void* __restrict__ bhh1,
    const void* __restrict__ cw1, const void* __restrict__ cb1,
    const void* __restrict__ cw2, const void* __restrict__ cb2,
    const int* __restrict__ flag,
    ushort* __restrict__ fifo, int* __restrict__ prog_p, int* __restrict__ prog_c,
    int F, void* __restrict__ out)
{
    __shared__ __align__(16) ushort sA[2][BT * H0STR]; // prod: h0+x; cons: staged h0
    __shared__ __align__(16) ushort sB[2][BT * H1STR]; // cons: h1 recurrence
    __shared__ float rs[BT * 64];                      // cons: classifier hidden

    const bool m32 = (*flag) != 0;
    const int tid  = threadIdx.x;
    const int w    = tid >> 6;
    const int lane = tid & 63;
    const int quad = lane >> 4;
    const int l16  = lane & 15;

    if ((int)blockIdx.x < NP) {
        // ================= PRODUCER: layer 0 =================
        const int p   = blockIdx.x;
        const int bt0 = p * BT;
        ushort* myfifo = fifo + (long)p * F * (BT * H_);

        // stage x(0) into sA[0] cols 128..159; zeros into sA[1]
        for (int i = tid; i < BT * 32; i += BLK) {
            int row = i >> 5, cc = i & 31;
            ushort v0 = (cc < 5) ? f2b(ldf(x, ((long)(bt0 + row) * T_) * D_ + cc, m32))
                                 : (ushort)0;
            sA[0][row * H0STR + 128 + cc] = v0;
            sA[1][row * H0STR + 128 + cc] = 0;
        }

        // weights: w_hh0 frags + x-tile frags (registers; ~150 regs/wave total)
        bf16x8 wh0c[4][4];
        bf16x8 xbf[4];
        float  b0v[4];
#pragma unroll
        for (int g = 0; g < 4; ++g) {
            const int n = g * 128 + w * 16 + l16;
#pragma unroll
            for (int kt = 0; kt < 4; ++kt)
                wh0c[g][kt] = ldfrag(whh0, (long)n * 128 + kt * 32 + quad * 8, m32);
            union { ushort u[8]; bf16x8 v; } xt;
#pragma unroll
            for (int j = 0; j < 8; ++j) xt.u[j] = 0;
            if (quad == 0) {
#pragma unroll
                for (int j = 0; j < 5; ++j) xt.u[j] = f2b(ldf(wih0, (long)n * D_ + j, m32));
            }
            xbf[g] = xt.v;
            b0v[g] = ldf(bih0, n, m32) + ldf(bhh0, n, m32);
        }
        __syncthreads();

        bf16x8 h0f[4];
        {
            uint4 z = make_uint4(0, 0, 0, 0);
            h0f[0] = h0f[1] = h0f[2] = h0f[3] = __builtin_bit_cast(bf16x8, z);
        }
        f32x4 c0 = splat4(0.f);
        const int xr = tid / 5, xc = tid - (tid / 5) * 5;

#pragma unroll 1
        for (int t = 0; t < T_; ++t) {
            const int rb = t & 1, wb = (t + 1) & 1;
            if ((t & (CH - 1)) == 0 && t > 0) {
                if (tid == 0) {
                    // publish steps < t (all FIFO stores drained by prior barrier)
                    __hip_atomic_store(&prog_p[p], t, __ATOMIC_RELEASE,
                                       __HIP_MEMORY_SCOPE_AGENT);
                    int need = t + CH - F;   // ring WAR throttle
                    if (need > 0)
                        while (__hip_atomic_load(&prog_c[p], __ATOMIC_ACQUIRE,
                                                 __HIP_MEMORY_SCOPE_AGENT) < need)
                            __builtin_amdgcn_s_sleep(2);
                }
                __syncthreads();
            }
            float xv = 0.f;
            const bool stage = (tid < 80) && (t < T_ - 1);
            if (stage) xv = ldf(x, ((long)(bt0 + xr) * T_ + (t + 1)) * D_ + xc, m32);

            f32x4 a[4];
#pragma unroll
            for (int g = 0; g < 4; ++g) a[g] = splat4(b0v[g]);
#pragma unroll
            for (int kt = 0; kt < 4; ++kt)
#pragma unroll
                for (int g = 0; g < 4; ++g)
                    a[g] = __builtin_amdgcn_mfma_f32_16x16x32_bf16(
                        h0f[kt], wh0c[g][kt], a[g], 0, 0, 0);
            {
                bf16x8 ha4 = ld16(&sA[rb][l16 * H0STR + 128 + quad * 8]);
#pragma unroll
                for (int g = 0; g < 4; ++g)
                    a[g] = __builtin_amdgcn_mfma_f32_16x16x32_bf16(
                        ha4, xbf[g], a[g], 0, 0, 0);
            }
            ushort* fs = myfifo + (long)(t & (F - 1)) * (BT * H_);
#pragma unroll
            for (int r = 0; r < 4; ++r) {
                float iv = sigf(a[0][r]), fv = sigf(a[1][r]);
                float gv = tanhf_(a[2][r]), ov = sigf(a[3][r]);
                float cv = fv * c0[r] + iv * gv;
                c0[r] = cv;
                ushort hv = f2b(ov * tanhf_(cv));
                int row = quad * 4 + r;
                sA[wb][row * H0STR + w * 16 + l16] = hv;
                fs[row * H_ + w * 16 + l16] = hv;       // FIFO (pre-barrier)
            }
            if (stage) sA[wb][xr * H0STR + 128 + xc] = f2b(xv);
            __syncthreads();
#pragma unroll
            for (int kt = 0; kt < 4; ++kt)
                h0f[kt] = ld16(&sA[wb][l16 * H0STR + kt * 32 + quad * 8]);
        }
        if (tid == 0)
            __hip_atomic_store(&prog_p[p], T_, __ATOMIC_RELEASE,
                               __HIP_MEMORY_SCOPE_AGENT);
    } else {
        // ================= CONSUMER: layer 1 + classifier =================
        const int p   = blockIdx.x - NP;
        const int bt0 = p * BT;
        const ushort* myfifo = fifo + (long)p * F * (BT * H_);

        // zero h1(-1)
        for (int i = tid; i < BT * H_; i += BLK) {
            int row = i >> 7, cc = i & 127;
            sB[0][row * H1STR + cc] = 0;
        }

        // weights: w_ih1 + w_hh1 frags (~190 regs/wave total)
        bf16x8 wi1f[4][4], wh1f[4][4];
        float  b1v[4];
#pragma unroll
        for (int g = 0; g < 4; ++g) {
            const int n = g * 128 + w * 16 + l16;
#pragma unroll
            for (int kt = 0; kt < 4; ++kt) {
                wi1f[g][kt] = ldfrag(wih1, (long)n * 128 + kt * 32 + quad * 8, m32);
                wh1f[g][kt] = ldfrag(wih1 == whh1 ? whh1 : whh1,
                                     (long)n * 128 + kt * 32 + quad * 8, m32);
            }
            b1v[g] = ldf(bih1, n, m32) + ldf(bhh1, n, m32);
        }

        // wait for first two chunks, then stage h0(0)
        if (tid == 0) {
            while (__hip_atomic_load(&prog_p[p], __ATOMIC_ACQUIRE,
                                     __HIP_MEMORY_SCOPE_AGENT) < 2 * CH)
                __builtin_amdgcn_s_sleep(2);
        }
        __syncthreads();
        {
            int row = tid >> 5, col4 = (tid & 31) * 4;
            uint2 d = *(const uint2*)(myfifo + tid * 4);
            *(uint2*)&sA[0][row * H0STR + col4] = d;
        }
        __syncthreads();

        f32x4 c1 = splat4(0.f);

#pragma unroll 1
        for (int t = 0; t < T_; ++t) {
            const int rb = t & 1, wb = (t + 1) & 1;
            // chunk boundary BEFORE prefetching into the next chunk:
            // acquire-invalidate precedes every read of newly-ready slots.
            if (((t + 1) & (CH - 1)) == 0 && t + 1 < T_) {
                if (tid == 0) {
                    int target = t + 1 + CH;
                    if (target > T_) target = T_;
                    while (__hip_atomic_load(&prog_p[p], __ATOMIC_ACQUIRE,
                                             __HIP_MEMORY_SCOPE_AGENT) < target)
                        __builtin_amdgcn_s_sleep(2);
                    __hip_atomic_store(&prog_c[p], t + 1, __ATOMIC_RELEASE,
                                       __HIP_MEMORY_SCOPE_AGENT);
                }
                __syncthreads();
            }
            // prefetch h0(t+1)
            uint2 pf = make_uint2(0, 0);
            const bool hn = (t + 1 < T_);
            if (hn) pf = *(const uint2*)(myfifo
                          + (long)((t + 1) & (F - 1)) * (BT * H_) + tid * 4);

            f32x4 a[4];
#pragma unroll
            for (int g = 0; g < 4; ++g) a[g] = splat4(b1v[g]);
#pragma unroll
            for (int kt = 0; kt < 4; ++kt) {
                bf16x8 h0a = ld16(&sA[rb][l16 * H0STR + kt * 32 + quad * 8]);
#pragma unroll
                for (int g = 0; g < 4; ++g)
                    a[g] = __builtin_amdgcn_mfma_f32_16x16x32_bf16(
                        h0a, wi1f[g][kt], a[g], 0, 0, 0);
            }
#pragma unroll
            for (int kt = 0; kt < 4; ++kt) {
                bf16x8 hb = ld16(&sB[rb][l16 * H1STR + kt * 32 + quad * 8]);
#pragma unroll
                for (int g = 0; g < 4; ++g)
                    a[g] = __builtin_amdgcn_mfma_f32_16x16x32_bf16(
                        hb, wh1f[g][kt], a[g], 0, 0, 0);
            }
#pragma unroll
            for (int r = 0; r < 4; ++r) {
                float iv = sigf(a[0][r]), fv = sigf(a[1][r]);
                float gv = tanhf_(a[2][r]), ov = sigf(a[3][r]);
                float cv = fv * c1[r] + iv * gv;
                c1[r] = cv;
                sB[wb][(quad * 4 + r) * H1STR + w * 16 + l16] = f2b(ov * tanhf_(cv));
            }
            if (hn) {
                int row = tid >> 5, col4 = (tid & 31) * 4;
                *(uint2*)&sA[wb][row * H0STR + col4] = pf;
            }
            __syncthreads();
        }

        // h1(T-1) is in sB[0]  (t=511: wb=0)
        if (tid < 256) {
            int m = tid >> 4, j0 = (tid & 15) * 4;
            float s0 = ldf(cb1, j0, m32), s1 = ldf(cb1, j0 + 1, m32);
            float s2 = ldf(cb1, j0 + 2, m32), s3 = ldf(cb1, j0 + 3, m32);
            const ushort* hr = &sB[0][m * H1STR];
#pragma unroll 4
            for (int k = 0; k < 128; ++k) {
                float hv = b2f(hr[k]);
                s0 += hv * ldf(cw1, (long)j0 * 128 + k, m32);
                s1 += hv * ldf(cw1, (long)(j0 + 1) * 128 + k, m32);
                s2 += hv * ldf(cw1, (long)(j0 + 2) * 128 + k, m32);
                s3 += hv * ldf(cw1, (long)(j0 + 3) * 128 + k, m32);
            }
            rs[m * 64 + j0]     = fmaxf(s0, 0.f);
            rs[m * 64 + j0 + 1] = fmaxf(s1, 0.f);
            rs[m * 64 + j0 + 2] = fmaxf(s2, 0.f);
            rs[m * 64 + j0 + 3] = fmaxf(s3, 0.f);
        }
        __syncthreads();
        if (tid < 160) {
            int m = tid / 10, cc = tid - m * 10;
            float s = ldf(cb2, cc, m32);
#pragma unroll
            for (int j = 0; j < 64; ++j)
                s += rs[m * 64 + j] * ldf(cw2, (long)cc * 64 + j, m32);
            long oi = (long)(bt0 + m) * C_ + cc;
            if (m32) ((float*)out)[oi] = s; else ((ushort*)out)[oi] = f2b(s);
        }
        for (int idx = tid; idx < BT * H_; idx += BLK) {
            int m = idx >> 7, k = idx & 127;
            float v = b2f(sB[0][m * H1STR + k]);
            long oi = (long)B_ * C_ + (long)(bt0 + m) * H_ + k;
            if (m32) ((float*)out)[oi] = v; else ((ushort*)out)[oi] = f2b(v);
        }
    }
}

// =====================================================================
// Fallback: proven R5 monolithic kernel (used when ws too small for FIFO)
// =====================================================================
__global__ __launch_bounds__(BLK, 2) void lstm2_mono(
    const void* __restrict__ x,
    const void* __restrict__ wih0, const void* __restrict__ whh0,
    const void* __restrict__ bih0, const void* __restrict__ bhh0,
    const void* __restrict__ wih1, const void* __restrict__ whh1,
    const void* __restrict__ bih1, const void* __restrict__ bhh1,
    const void* __restrict__ cw1, const void* __restrict__ cb1,
    const void* __restrict__ cw2, const void* __restrict__ cb2,
    const int* __restrict__ flag, void* __restrict__ out)
{
    __shared__ __align__(16) ushort h0s[2][BT * H0STR];
    __shared__ __align__(16) ushort h1s[2][BT * H1STR];
    __shared__ float rs[BT * 64];
    __shared__ uint4 xstash[4 * 8 * 64];

    const bool m32 = (*flag) != 0;
    const int tid  = threadIdx.x;
    const int w    = tid >> 6;
    const int lane = tid & 63;
    const int quad = lane >> 4;
    const int l16  = lane & 15;
    const int bt0  = blockIdx.x * BT;

    for (int i = tid; i < BT * 32; i += BLK) {
        int row = i >> 5, cc = i & 31;
        ushort v0 = (cc < 5) ? f2b(ldf(x, ((long)(bt0 + row) * T_) * D_ + cc, m32)) : (ushort)0;
        h0s[0][row * H0STR + 128 + cc] = v0;
        h0s[1][row * H0STR + 128 + cc] = 0;
    }
    for (int i = tid; i < BT * H_; i += BLK) {
        int row = i >> 7, cc = i & 127;
        h1s[1][row * H1STR + cc] = 0;
    }

    bf16x8 wh0c[4][4], wi1f[4][4], wh1f[4][4];
    float  b0v[4], b1v[4];
#pragma unroll
    for (int g = 0; g < 4; ++g) {
        const int n = g * 128 + w * 16 + l16;
#pragma unroll
        for (int kt = 0; kt < 4; ++kt) {
            wh0c[g][kt] = ldfrag(whh0, (long)n * 128 + kt * 32 + quad * 8, m32);
            wi1f[g][kt] = ldfrag(wih1, (long)n * 128 + kt * 32 + quad * 8, m32);
            wh1f[g][kt] = ldfrag(whh1, (long)n * 128 + kt * 32 + quad * 8, m32);
        }
        union { ushort u[8]; uint4 q; } xt;
        xt.q = make_uint4(0, 0, 0, 0);
        if (quad == 0) {
#pragma unroll
            for (int j = 0; j < 5; ++j) xt.u[j] = f2b(ldf(wih0, (long)n * D_ + j, m32));
        }
        xstash[(g * 8 + w) * 64 + lane] = xt.q;
        b0v[g] = ldf(bih0, n, m32) + ldf(bhh0, n, m32);
        b1v[g] = ldf(bih1, n, m32) + ldf(bhh1, n, m32);
    }
    __syncthreads();

    bf16x8 h0f[4];
    {
        uint4 z = make_uint4(0, 0, 0, 0);
        h0f[0] = h0f[1] = h0f[2] = h0f[3] = __builtin_bit_cast(bf16x8, z);
    }
    f32x4 c0 = splat4(0.f), c1 = splat4(0.f);
    const int xr = tid / 5, xc = tid - (tid / 5) * 5;

#pragma unroll 1
    for (int t = 0; t < T_; ++t) {
        const int wb = (t + 1) & 1, rb = t & 1;
        float xv = 0.f;
        const bool stage = (tid < 80) && (t < T_ - 1);
        if (stage) xv = ldf(x, ((long)(bt0 + xr) * T_ + (t + 1)) * D_ + xc, m32);

        f32x4 a[4];
#pragma unroll
        for (int g = 0; g < 4; ++g) a[g] = splat4(b0v[g]);
#pragma unroll
        for (int kt = 0; kt < 4; ++kt)
#pragma unroll
            for (int g = 0; g < 4; ++g)
                a[g] = __builtin_amdgcn_mfma_f32_16x16x32_bf16(
                    h0f[kt], wh0c[g][kt], a[g], 0, 0, 0);
        {
            bf16x8 ha4 = ld16(&h0s[rb][l16 * H0STR + 128 + quad * 8]);
#pragma unroll
            for (int g = 0; g < 4; ++g) {
                bf16x8 xb = __builtin_bit_cast(bf16x8, xstash[(g * 8 + w) * 64 + lane]);
                a[g] = __builtin_amdgcn_mfma_f32_16x16x32_bf16(ha4, xb, a[g], 0, 0, 0);
            }
        }
        ushort h0w[4];
#pragma unroll
        for (int r = 0; r < 4; ++r) {
            float iv = sigf(a[0][r]), fv = sigf(a[1][r]);
            float gv = tanhf_(a[2][r]), ov = sigf(a[3][r]);
            float cv = fv * c0[r] + iv * gv;
            c0[r] = cv;
            h0w[r] = f2b(ov * tanhf_(cv));
        }
#pragma unroll
        for (int r = 0; r < 4; ++r)
            h0s[wb][(quad * 4 + r) * H0STR + w * 16 + l16] = h0w[r];
        if (stage) h0s[wb][xr * H0STR + 128 + xc] = f2b(xv);
        __syncthreads();
#pragma unroll
        for (int kt = 0; kt < 4; ++kt)
            h0f[kt] = ld16(&h0s[wb][l16 * H0STR + kt * 32 + quad * 8]);

#pragma unroll
        for (int g = 0; g < 4; ++g) a[g] = splat4(b1v[g]);
#pragma unroll
        for (int kt = 0; kt < 4; ++kt)
#pragma unroll
            for (int g = 0; g < 4; ++g)
                a[g] = __builtin_amdgcn_mfma_f32_16x16x32_bf16(
                    h0f[kt], wi1f[g][kt], a[g], 0, 0, 0);
#pragma unroll
        for (int kt = 0; kt < 4; ++kt) {
            bf16x8 hb = ld16(&h1s[wb][l16 * H1STR + kt * 32 + quad * 8]);
#pragma unroll
            for (int g = 0; g < 4; ++g)
                a[g] = __builtin_amdgcn_mfma_f32_16x16x32_bf16(
                    hb, wh1f[g][kt], a[g], 0, 0, 0);
        }
#pragma unroll
        for (int r = 0; r < 4; ++r) {
            float iv = sigf(a[0][r]), fv = sigf(a[1][r]);
            float gv = tanhf_(a[2][r]), ov = sigf(a[3][r]);
            float cv = fv * c1[r] + iv * gv;
            c1[r] = cv;
            h1s[wb ^ 1][(quad * 4 + r) * H1STR + w * 16 + l16] = f2b(ov * tanhf_(cv));
        }
    }
    __syncthreads();

    if (tid < 256) {
        int m = tid >> 4, j0 = (tid & 15) * 4;
        float s0 = ldf(cb1, j0, m32), s1 = ldf(cb1, j0 + 1, m32);
        float s2 = ldf(cb1, j0 + 2, m32), s3 = ldf(cb1, j0 + 3, m32);
        const ushort* hr = &h1s[1][m * H1STR];
#pragma unroll 4
        for (int k = 0; k < 128; ++k) {
            float hv = b2f(hr[k]);
            s0 += hv * ldf(cw1, (long)j0 * 128 + k, m32);
            s1 += hv * ldf(cw1, (long)(j0 + 1) * 128 + k, m32);
            s2 += hv * ldf(cw1, (long)(j0 + 2) * 128 + k, m32);
            s3 += hv * ldf(cw1, (long)(j0 + 3) * 128 + k, m32);
        }
        rs[m * 64 + j0]     = fmaxf(s0, 0.f);
        rs[m * 64 + j0 + 1] = fmaxf(s1, 0.f);
        rs[m * 64 + j0 + 2] = fmaxf(s2, 0.f);
        rs[m * 64 + j0 + 3] = fmaxf(s3, 0.f);
    }
    __syncthreads();
    if (tid < 160) {
        int m = tid / 10, cc = tid - m * 10;
        float s = ldf(cb2, cc, m32);
#pragma unroll
        for (int j = 0; j < 64; ++j) s += rs[m * 64 + j] * ldf(cw2, (long)cc * 64 + j, m32);
        long oi = (long)(bt0 + m) * C_ + cc;
        if (m32) ((float*)out)[oi] = s; else ((ushort*)out)[oi] = f2b(s);
    }
    for (int idx = tid; idx < BT * H_; idx += BLK) {
        int m = idx >> 7, k = idx & 127;
        float v = b2f(h1s[1][m * H1STR + k]);
        long oi = (long)B_ * C_ + (long)(bt0 + m) * H_ + k;
        if (m32) ((float*)out)[oi] = v; else ((ushort*)out)[oi] = f2b(v);
    }
}

extern "C" void kernel_launch(void* const* d_in, const int* in_sizes, int n_in,
                              void* d_out, int out_size, void* d_ws, size_t ws_size,
                              hipStream_t stream) {
    (void)in_sizes; (void)n_in; (void)out_size;
    int* prog  = (int*)d_ws;                       // prog_p[128] | prog_c[128]
    int* flag  = (int*)((char*)d_ws + 4096);
    ushort* fifo = (ushort*)((char*)d_ws + 8192);

    hipLaunchKernelGGL(detect_dtype, dim3(1), dim3(256), 0, stream,
                       (const ushort*)d_in[2], flag);

    const size_t slot = (size_t)NP * BT * H_ * sizeof(ushort); // all pairs, 1 step
    int F = 0;
    if (ws_size >= 8192 + 64 * slot) F = 64;
    else if (ws_size >= 8192 + 32 * slot) F = 32;

    if (F) {
        hipLaunchKernelGGL(init_flags, dim3(1), dim3(256), 0, stream, prog);
        hipLaunchKernelGGL(lstm2_pipe, dim3(2 * NP), dim3(BLK), 0, stream,
                           d_in[0], d_in[1], d_in[2], d_in[3], d_in[4],
                           d_in[5], d_in[6], d_in[7], d_in[8],
                           d_in[9], d_in[10], d_in[11], d_in[12],
                           (const int*)flag, fifo, prog, prog + NP, F, d_out);
    } else {
        hipLaunchKernelGGL(lstm2_mono, dim3(B_ / BT), dim3(BLK), 0, stream,
                           d_in[0], d_in[1], d_in[2], d_in[3], d_in[4],
                           d_in[5], d_in[6], d_in[7], d_in[8],
                           d_in[9], d_in[10], d_in[11], d_in[12],
                           (const int*)flag, d_out);
    }
}